// Round 12
// baseline (176.235 us; speedup 1.0000x reference)
//
#include <hip/hip_runtime.h>
#include <hip/hip_bf16.h>

#define BQ 8
#define DIM 512
#define NN 2048
#define MM 2048
#define MSPLIT 16         // m tiles of 128 -> grid 16x16x8 = 2048 blocks

typedef __attribute__((ext_vector_type(8))) short short8;
typedef __attribute__((ext_vector_type(8))) unsigned short ushort8;
typedef __attribute__((ext_vector_type(4))) float floatx4;

// async global->LDS, 16B per lane, dest = wave-uniform base + lane*16.
// imm offset must be ICE at call site (R8) -> fold k-offset into pointer.
#define GLOAD_LDS(gp, lp) \
    __builtin_amdgcn_global_load_lds( \
        (const __attribute__((address_space(1))) void*)(gp), \
        (__attribute__((address_space(3))) void*)(lp), 16, 0, 0)

// ws layout:
//   [0, 4MiB)        : partials [b][qt][n] float4 {l, o0, o1, o2}  (16 slots/b)
//   [4MiB, 20MiB)    : Abf  [B][N][D] bf16  (transposed src_embedding)
//   [20MiB, 36MiB)   : Bbf  [B][M][D] bf16  (transposed tgt_embedding)
//   [36MiB, +9KiB)   : red  [b][chunk][18]  stage-1 reduction sums

static __device__ __forceinline__ unsigned short f2bf(float x) {
    __hip_bfloat16 h = __float2bfloat16(x);
    return *(unsigned short*)&h;
}

// ---------------- transpose + fp32->bf16 cast ----------------
__global__ __launch_bounds__(256) void transpose_cast_kernel(
    const float* __restrict__ src_emb,   // [B, D, N]
    const float* __restrict__ tgt_emb,   // [B, D, M]
    __hip_bfloat16* __restrict__ Abf,    // [B, N, D]
    __hip_bfloat16* __restrict__ Bbf)    // [B, M, D]
{
    const int n0 = blockIdx.x * 64;
    const int d0 = blockIdx.y * 64;
    const int b  = blockIdx.z & 7;
    const int which = blockIdx.z >> 3;

    const float* in = (which == 0 ? src_emb : tgt_emb) + (size_t)b * DIM * NN;
    __hip_bfloat16* out = (which == 0 ? Abf : Bbf) + (size_t)b * NN * DIM;

    __shared__ float tl[64][65];

    const int t = threadIdx.x;

    {
        const int u = t & 15;
        const int r = t >> 4;
        #pragma unroll
        for (int rr = r; rr < 64; rr += 16) {
            float4 v = *(const float4*)&in[(size_t)(d0 + rr) * NN + n0 + u * 4];
            tl[rr][u * 4 + 0] = v.x;
            tl[rr][u * 4 + 1] = v.y;
            tl[rr][u * 4 + 2] = v.z;
            tl[rr][u * 4 + 3] = v.w;
        }
    }
    __syncthreads();

    {
        const int u = t & 7;          // d-octet 0..7
        const int r = t >> 3;         // 0..31
        #pragma unroll
        for (int rn = r; rn < 64; rn += 32) {
            ushort8 o;
            #pragma unroll
            for (int j = 0; j < 8; j++)
                o[j] = f2bf(tl[u * 8 + j][rn]);
            *(ushort8*)&out[(size_t)(n0 + rn) * DIM + d0 + u * 8] = o;
        }
    }
}

// ---------------- MFMA attention + soft correspondence ----------------
// grid (16 nt, 16 qt, 8 b) = 2048 blocks. Block = 128n x 128m.
// R12: 2x2 wave split — wave w covers n-half (w>>1)*64, m-half (w&1)*64,
// tile 64x64. LDS reads per wave per kt: 4A+4B per ks x2 = 16 b128 for
// 32 MFMAs, vs R9's 20 (n-stacked 32x128 tile) — attn is LDS-read bound,
// perimeter/area wins. BOTH A and B stay DMA-staged (R10's regression was
// direct-global A loads exposing raw L2 latency, NOT the 2x2 split; its
// LDS-combine epilogue was bit-identical). XOR chunk swizzle: LDS[row][c]
// holds global chunk c^(row&7); read phys (ks*4+quad)^(lm&7) -> 2 lanes
// per bank-group = free (0 conflicts measured R9/R11).
// launch_bounds(256,2) only — (256,4) forced 64 VGPRs, spilled acc (R5).
__global__ __launch_bounds__(256, 2) void attn_mfma_kernel(
    const __hip_bfloat16* __restrict__ Abf,  // [B, N, D]
    const __hip_bfloat16* __restrict__ Bbf,  // [B, M, D]
    const float* __restrict__ tgt,           // [B, 3, M]
    float* __restrict__ part)                // [b][qt][n] float4
{
    const int nt = blockIdx.x;      // 0..15  n tile of 128
    const int qt = blockIdx.y;      // 0..15  m tile of 128
    const int b  = blockIdx.z;      // 0..7
    const int t  = threadIdx.x;
    const int wave = t >> 6;
    const int lane = t & 63;
    const int lm   = lane & 15;
    const int quad = lane >> 4;
    const int nh = wave >> 1;       // n-half 0/1
    const int mh = wave & 1;        // m-half 0/1
    const int wn = wave * 32;       // this wave's STAGING row range

    // 128 rows x 8 chunks x 8 shorts (16B); row stride 128B, unpadded
    __shared__ short As[128 * 64];
    __shared__ short Bs[128 * 64];
    __shared__ float4 sc4[2][128];          // per-m-half partial combine

    const __hip_bfloat16* Abase = Abf + ((size_t)(b * NN + nt * 128)) * DIM;
    const int m0 = qt * 128;
    const __hip_bfloat16* Bbase = Bbf + ((size_t)(b * MM + m0)) * DIM;
    const float* Tb = tgt + (size_t)b * 3 * MM;

    const float SCALE = 0.044194173824159216f * 1.4426950408889634f;

    // staging geometry: lane = r8*8 + c8 covers row (wn+r8 [+8/call]), phys
    // chunk c8, fetching global chunk c8^r8 ((wn+r8)&7 == r8, wn 8-aligned)
    const int r8 = lane >> 3;
    const int c8 = lane & 7;
    const int cc = c8 ^ r8;
    const __hip_bfloat16* gA = Abase + (size_t)(wn + r8) * DIM + cc * 8;
    const __hip_bfloat16* gB = Bbase + (size_t)(wn + r8) * DIM + cc * 8;
    short* lA = &As[wn * 64];
    short* lB = &Bs[wn * 64];

    floatx4 acc[4][4];
    #pragma unroll
    for (int i = 0; i < 4; i++)
        #pragma unroll
        for (int j = 0; j < 4; j++)
            acc[i][j] = (floatx4){0.f, 0.f, 0.f, 0.f};

    #pragma unroll
    for (int kt = 0; kt < 8; kt++) {     // d chunks of 64 elements
        #pragma unroll
        for (int i = 0; i < 4; i++) {    // 8 rows per issue, A and B
            GLOAD_LDS(gA + kt * 64 + (size_t)i * 8 * DIM, lA + i * 512);
            GLOAD_LDS(gB + kt * 64 + (size_t)i * 8 * DIM, lB + i * 512);
        }
        __syncthreads();

        #pragma unroll
        for (int ks = 0; ks < 2; ks++) {
            const int pc = (((ks * 4 + quad) ^ (lm & 7)) * 8);
            short8 af[4], bf[4];
            #pragma unroll
            for (int i = 0; i < 4; i++)
                af[i] = *(const short8*)&As[(nh * 64 + i * 16 + lm) * 64 + pc];
            #pragma unroll
            for (int j = 0; j < 4; j++)
                bf[j] = *(const short8*)&Bs[(mh * 64 + j * 16 + lm) * 64 + pc];
            #pragma unroll
            for (int i = 0; i < 4; i++)
                #pragma unroll
                for (int j = 0; j < 4; j++)
                    acc[i][j] = __builtin_amdgcn_mfma_f32_16x16x32_bf16(
                        af[i], bf[j], acc[i][j], 0, 0, 0);
        }
        __syncthreads();
    }

    // V columns for this wave's m-half (global, L2-hot)
    float v0[4], v1[4], v2[4];
    #pragma unroll
    for (int j = 0; j < 4; j++) {
        int vc = m0 + mh * 64 + j * 16 + lm;
        v0[j] = Tb[vc];
        v1[j] = Tb[MM + vc];
        v2[j] = Tb[2 * MM + vc];
    }

    // epilogue: exp, m-partial sums, lm-reduce, stash in LDS scratch
    // C/D layout (m89/m91): col = lane&15 (m), row = quad*4+reg (n)
    #pragma unroll
    for (int i = 0; i < 4; i++) {
        float l4[4] = {0,0,0,0};
        float o0[4] = {0,0,0,0};
        float o1[4] = {0,0,0,0};
        float o2[4] = {0,0,0,0};
        #pragma unroll
        for (int j = 0; j < 4; j++) {
            #pragma unroll
            for (int r = 0; r < 4; r++) {
                float e = __builtin_amdgcn_exp2f(acc[i][j][r] * SCALE);
                l4[r] += e;
                o0[r] += e * v0[j];
                o1[r] += e * v1[j];
                o2[r] += e * v2[j];
            }
        }
        #pragma unroll
        for (int m = 1; m <= 8; m <<= 1) {
            #pragma unroll
            for (int r = 0; r < 4; r++) {
                l4[r] += __shfl_xor(l4[r], m);
                o0[r] += __shfl_xor(o0[r], m);
                o1[r] += __shfl_xor(o1[r], m);
                o2[r] += __shfl_xor(o2[r], m);
            }
        }
        if (lm == 0) {
            #pragma unroll
            for (int r = 0; r < 4; r++)
                sc4[mh][nh * 64 + i * 16 + quad * 4 + r] =
                    make_float4(l4[r], o0[r], o1[r], o2[r]);
        }
    }
    __syncthreads();

    // combine the two m-halves, single coalesced store (format unchanged)
    if (t < 128) {
        float4 a = sc4[0][t], c = sc4[1][t];
        ((float4*)part)[(size_t)(b * MSPLIT + qt) * NN + nt * 128 + t] =
            make_float4(a.x + c.x, a.y + c.y, a.z + c.z, a.w + c.w);
    }
}

// ---------------- stage-1 reduce: 128 blocks ----------------
__global__ __launch_bounds__(128) void reduce1_kernel(
    const float* __restrict__ part,
    const float* __restrict__ src,       // [B,3,N]
    const float* __restrict__ tgt,       // [B,3,M]
    float* __restrict__ red)             // [b][chunk][18]
{
    const int chunk = blockIdx.x;        // 0..15
    const int b     = blockIdx.y;        // 0..7
    const int t     = threadIdx.x;       // 0..127
    const int n     = chunk * 128 + t;

    const float4* w4 = (const float4*)part;
    const float* S = src + (size_t)b * 3 * NN;
    const float* T = tgt + (size_t)b * 3 * MM;

    float l = 0.f, y0 = 0.f, y1 = 0.f, y2 = 0.f;
    #pragma unroll
    for (int q = 0; q < 16; q++) {
        float4 p = w4[(size_t)(b * 16 + q) * NN + n];
        l += p.x; y0 += p.y; y1 += p.z; y2 += p.w;
    }
    float inv = 1.0f / l;
    float c0 = y0 * inv, c1 = y1 * inv, c2 = y2 * inv;
    float s0 = S[n], s1 = S[NN + n], s2 = S[2 * NN + n];

    float vals[18];
    vals[0] = s0;  vals[1] = s1;  vals[2] = s2;
    vals[3] = c0;  vals[4] = c1;  vals[5] = c2;
    vals[6] = T[n]; vals[7] = T[MM + n]; vals[8] = T[2 * MM + n];
    vals[9]  = s0 * c0; vals[10] = s0 * c1; vals[11] = s0 * c2;
    vals[12] = s1 * c0; vals[13] = s1 * c1; vals[14] = s1 * c2;
    vals[15] = s2 * c0; vals[16] = s2 * c1; vals[17] = s2 * c2;

    #pragma unroll
    for (int m = 1; m <= 32; m <<= 1)
        #pragma unroll
        for (int c = 0; c < 18; c++)
            vals[c] += __shfl_xor(vals[c], m);

    __shared__ float w0[18];
    if (t == 64)
        #pragma unroll
        for (int c = 0; c < 18; c++) w0[c] = vals[c];
    __syncthreads();
    if (t == 0)
        #pragma unroll
        for (int c = 0; c < 18; c++)
            red[(size_t)(b * 16 + chunk) * 18 + c] = vals[c] + w0[c];
}

// ---------------- stage-2: combine 16 chunk-sums, Procrustes ----------------
__global__ __launch_bounds__(64) void procrustes_kernel(
    const float* __restrict__ red,       // [b][chunk][18]
    float* __restrict__ out)             // [72 R][24 t]
{
    const int b = blockIdx.x;
    const int t = threadIdx.x;

    __shared__ float res[18];
    if (t < 18) {
        float a = 0.f;
        #pragma unroll
        for (int q = 0; q < 16; q++)
            a += red[(size_t)(b * 16 + q) * 18 + t];
        res[t] = a;
    }
    __syncthreads();

    if (t == 0) {
        const float invN = 1.0f / (float)NN;
        float mus[3], muc[3], mut[3], H[3][3];
        for (int i = 0; i < 3; i++) {
            mus[i] = res[i] * invN;
            muc[i] = res[3 + i] * invN;
            mut[i] = res[6 + i] * invN;
        }
        for (int i = 0; i < 3; i++)
            for (int j = 0; j < 3; j++)
                H[i][j] = res[9 + i * 3 + j] - (float)NN * mus[i] * muc[j];

        float A[3][3];
        for (int i = 0; i < 3; i++)
            for (int j = 0; j < 3; j++)
                A[i][j] = H[0][i] * H[0][j] + H[1][i] * H[1][j] + H[2][i] * H[2][j];

        float V[3][3] = {{1,0,0},{0,1,0},{0,0,1}};
        for (int sweep = 0; sweep < 6; sweep++) {
            for (int pi = 0; pi < 3; pi++) {
                int p = (pi < 2) ? 0 : 1;
                int q = (pi == 0) ? 1 : 2;
                float apq = A[p][q];
                if (fabsf(apq) < 1e-30f) continue;
                float tau = (A[q][q] - A[p][p]) / (2.0f * apq);
                float tt = (tau >= 0.0f) ? 1.0f / (tau + sqrtf(1.0f + tau * tau))
                                         : -1.0f / (-tau + sqrtf(1.0f + tau * tau));
                float c = 1.0f / sqrtf(1.0f + tt * tt);
                float s = tt * c;
                for (int k = 0; k < 3; k++) {
                    float akp = A[k][p], akq = A[k][q];
                    A[k][p] = c * akp - s * akq;
                    A[k][q] = s * akp + c * akq;
                }
                for (int k = 0; k < 3; k++) {
                    float apk = A[p][k], aqk = A[q][k];
                    A[p][k] = c * apk - s * aqk;
                    A[q][k] = s * apk + c * aqk;
                }
                for (int k = 0; k < 3; k++) {
                    float vkp = V[k][p], vkq = V[k][q];
                    V[k][p] = c * vkp - s * vkq;
                    V[k][q] = s * vkp + c * vkq;
                }
            }
        }

        float lam[3] = {A[0][0], A[1][1], A[2][2]};
        int idx[3] = {0, 1, 2};
        for (int a = 0; a < 2; a++)
            for (int bb = 0; bb < 2 - a; bb++)
                if (lam[idx[bb]] < lam[idx[bb + 1]]) { int tmp = idx[bb]; idx[bb] = idx[bb + 1]; idx[bb + 1] = tmp; }

        float Vc[3][3], U[3][3];
        for (int c = 0; c < 3; c++) {
            float sv = sqrtf(fmaxf(lam[idx[c]], 0.0f));
            float isv = 1.0f / fmaxf(sv, 1e-20f);
            for (int r = 0; r < 3; r++) {
                Vc[r][c] = V[r][idx[c]];
                U[r][c] = (H[r][0] * V[0][idx[c]] + H[r][1] * V[1][idx[c]] + H[r][2] * V[2][idx[c]]) * isv;
            }
        }

        {
            float nrm = rsqrtf(U[0][0]*U[0][0] + U[1][0]*U[1][0] + U[2][0]*U[2][0]);
            for (int r = 0; r < 3; r++) U[r][0] *= nrm;
            float d01 = U[0][0]*U[0][1] + U[1][0]*U[1][1] + U[2][0]*U[2][1];
            for (int r = 0; r < 3; r++) U[r][1] -= d01 * U[r][0];
            nrm = rsqrtf(U[0][1]*U[0][1] + U[1][1]*U[1][1] + U[2][1]*U[2][1]);
            for (int r = 0; r < 3; r++) U[r][1] *= nrm;
            float d02 = U[0][0]*U[0][2] + U[1][0]*U[1][2] + U[2][0]*U[2][2];
            float d12 = U[0][1]*U[0][2] + U[1][1]*U[1][2] + U[2][1]*U[2][2];
            for (int r = 0; r < 3; r++) U[r][2] -= d02 * U[r][0] + d12 * U[r][1];
            nrm = rsqrtf(U[0][2]*U[0][2] + U[1][2]*U[1][2] + U[2][2]*U[2][2]);
            for (int r = 0; r < 3; r++) U[r][2] *= nrm;
        }

        float det = H[0][0]*(H[1][1]*H[2][2] - H[1][2]*H[2][1])
                  - H[0][1]*(H[1][0]*H[2][2] - H[1][2]*H[2][0])
                  + H[0][2]*(H[1][0]*H[2][1] - H[1][1]*H[2][0]);
        float sgn = (det < 0.0f) ? -1.0f : 1.0f;

        float R[3][3];
        for (int i = 0; i < 3; i++)
            for (int j = 0; j < 3; j++)
                R[i][j] = Vc[i][0]*U[j][0] + Vc[i][1]*U[j][1] + sgn * Vc[i][2]*U[j][2];

        for (int i = 0; i < 3; i++)
            for (int j = 0; j < 3; j++)
                out[b * 9 + i * 3 + j] = R[i][j];
        for (int i = 0; i < 3; i++)
            out[BQ * 9 + b * 3 + i] = mut[i] - (R[i][0]*mus[0] + R[i][1]*mus[1] + R[i][2]*mus[2]);
    }
}

extern "C" void kernel_launch(void* const* d_in, const int* in_sizes, int n_in,
                              void* d_out, int out_size, void* d_ws, size_t ws_size,
                              hipStream_t stream) {
    const float* src_emb = (const float*)d_in[0];
    const float* tgt_emb = (const float*)d_in[1];
    const float* src     = (const float*)d_in[2];
    const float* tgt     = (const float*)d_in[3];
    float* out = (float*)d_out;

    float* part = (float*)d_ws;                                            // 4 MiB
    __hip_bfloat16* Abf = (__hip_bfloat16*)((char*)d_ws + (4 << 20));       // 16 MiB
    __hip_bfloat16* Bbf = (__hip_bfloat16*)((char*)d_ws + (20 << 20));      // 16 MiB
    float* red = (float*)((char*)d_ws + (36 << 20));                        // 9 KiB

    dim3 gridT(NN / 64, DIM / 64, 2 * BQ);    // 32 x 8 x 16 = 4096 blocks
    transpose_cast_kernel<<<gridT, 256, 0, stream>>>(src_emb, tgt_emb, Abf, Bbf);

    dim3 gridA(NN / 128, MSPLIT, BQ);         // 16 x 16 x 8 = 2048 blocks
    attn_mfma_kernel<<<gridA, 256, 0, stream>>>(Abf, Bbf, tgt, part);

    dim3 gridR(16, BQ);                       // 128 blocks
    reduce1_kernel<<<gridR, 128, 0, stream>>>(part, src, tgt, red);

    procrustes_kernel<<<BQ, 64, 0, stream>>>(red, out);
}

// Round 13
// 169.007 us; speedup vs baseline: 1.0428x; 1.0428x over previous
//
#include <hip/hip_runtime.h>
#include <hip/hip_bf16.h>

#define BQ 8
#define DIM 512
#define NN 2048
#define MM 2048
#define MSPLIT 16         // m tiles of 128

typedef __attribute__((ext_vector_type(8))) short short8;
typedef __attribute__((ext_vector_type(8))) unsigned short ushort8;
typedef __attribute__((ext_vector_type(4))) float floatx4;

// async global->LDS, 16B per lane, dest = wave-uniform base + lane*16.
// imm offset must be ICE at call site (R8) -> fold k-offset into pointer.
#define GLOAD_LDS(gp, lp) \
    __builtin_amdgcn_global_load_lds( \
        (const __attribute__((address_space(1))) void*)(gp), \
        (__attribute__((address_space(3))) void*)(lp), 16, 0, 0)

// ws layout:
//   [0, 4MiB)        : partials [b][qt][n] float4 {l, o0, o1, o2}  (16 slots/b)
//   [4MiB, 20MiB)    : Abf  [B][N][D] bf16  (transposed src_embedding)
//   [20MiB, 36MiB)   : Bbf  [B][M][D] bf16  (transposed tgt_embedding)
//   [36MiB, +9KiB)   : red  [b][chunk][18]  stage-1 reduction sums

static __device__ __forceinline__ unsigned short f2bf(float x) {
    __hip_bfloat16 h = __float2bfloat16(x);
    return *(unsigned short*)&h;
}

// ---------------- transpose + fp32->bf16 cast ----------------
__global__ __launch_bounds__(256) void transpose_cast_kernel(
    const float* __restrict__ src_emb,   // [B, D, N]
    const float* __restrict__ tgt_emb,   // [B, D, M]
    __hip_bfloat16* __restrict__ Abf,    // [B, N, D]
    __hip_bfloat16* __restrict__ Bbf)    // [B, M, D]
{
    const int n0 = blockIdx.x * 64;
    const int d0 = blockIdx.y * 64;
    const int b  = blockIdx.z & 7;
    const int which = blockIdx.z >> 3;

    const float* in = (which == 0 ? src_emb : tgt_emb) + (size_t)b * DIM * NN;
    __hip_bfloat16* out = (which == 0 ? Abf : Bbf) + (size_t)b * NN * DIM;

    __shared__ float tl[64][65];

    const int t = threadIdx.x;

    {
        const int u = t & 15;
        const int r = t >> 4;
        #pragma unroll
        for (int rr = r; rr < 64; rr += 16) {
            float4 v = *(const float4*)&in[(size_t)(d0 + rr) * NN + n0 + u * 4];
            tl[rr][u * 4 + 0] = v.x;
            tl[rr][u * 4 + 1] = v.y;
            tl[rr][u * 4 + 2] = v.z;
            tl[rr][u * 4 + 3] = v.w;
        }
    }
    __syncthreads();

    {
        const int u = t & 7;          // d-octet 0..7
        const int r = t >> 3;         // 0..31
        #pragma unroll
        for (int rn = r; rn < 64; rn += 32) {
            ushort8 o;
            #pragma unroll
            for (int j = 0; j < 8; j++)
                o[j] = f2bf(tl[u * 8 + j][rn]);
            *(ushort8*)&out[(size_t)(n0 + rn) * DIM + d0 + u * 8] = o;
        }
    }
}

// ---------------- MFMA attention + soft correspondence ----------------
// R13: 256n x 128m block, 8 waves (512 thr), per-wave structure = R9 verbatim
// (32n x 128m, own partial slot, full-m sums). Rationale: R12 falsified the
// LDS-read-count model; arithmetic says no pipe saturates -> barrier/drain
// bound. Bigger block amortizes staged bytes + barrier drains over 2x output
// (48KB/kt for 2x rows vs 32KB for 1x). Staging: 8 waves x 32 A-rows,
// 8 waves x 16 B-rows = 6 GLOADs/wave/kt. XOR chunk swizzle as R9 (LDS[row]
// phys chunk c holds global chunk c^(row&7); read phys (ks*4+quad)^(lm&7);
// 0 conflicts measured R9/R11/R12).
// launch_bounds(512,2): VGPR cap 256, no pressure (R9 was 56; R5 lesson:
// never demand occupancy the accumulators can't afford).
__global__ __launch_bounds__(512, 2) void attn_mfma_kernel(
    const __hip_bfloat16* __restrict__ Abf,  // [B, N, D]
    const __hip_bfloat16* __restrict__ Bbf,  // [B, M, D]
    const float* __restrict__ tgt,           // [B, 3, M]
    float* __restrict__ part)                // [b][qt][n] float4
{
    const int nt = blockIdx.x;      // 0..7   n tile of 256
    const int qt = blockIdx.y;      // 0..15  m tile of 128
    const int b  = blockIdx.z;      // 0..7
    const int t  = threadIdx.x;     // 0..511
    const int wave = t >> 6;        // 0..7
    const int lane = t & 63;
    const int lm   = lane & 15;
    const int quad = lane >> 4;
    const int wn   = wave * 32;     // wave's n offset in the 256 tile
    const int bw   = wave * 16;     // wave's B staging row base

    // A: 256 rows x 8 chunks x 16B = 32KB; B: 128 rows = 16KB; unpadded
    __shared__ short As[256 * 64];
    __shared__ short Bs[128 * 64];

    const __hip_bfloat16* Abase = Abf + ((size_t)(b * NN + nt * 256)) * DIM;
    const int m0 = qt * 128;
    const __hip_bfloat16* Bbase = Bbf + ((size_t)(b * MM + m0)) * DIM;
    const float* Tb = tgt + (size_t)b * 3 * MM;

    const float SCALE = 0.044194173824159216f * 1.4426950408889634f;

    // staging geometry: lane = r8*8 + c8 covers row (+r8, +8/call), phys
    // chunk c8, fetching global chunk c8^r8 (row bases are 8-aligned)
    const int r8 = lane >> 3;
    const int c8 = lane & 7;
    const int cc = c8 ^ r8;
    const __hip_bfloat16* gA = Abase + (size_t)(wn + r8) * DIM + cc * 8;
    const __hip_bfloat16* gB = Bbase + (size_t)(bw + r8) * DIM + cc * 8;
    short* lA = &As[wn * 64];
    short* lB = &Bs[bw * 64];

    floatx4 acc[2][8];
    #pragma unroll
    for (int i = 0; i < 2; i++)
        #pragma unroll
        for (int j = 0; j < 8; j++)
            acc[i][j] = (floatx4){0.f, 0.f, 0.f, 0.f};

    #pragma unroll
    for (int kt = 0; kt < 8; kt++) {     // d chunks of 64 elements
        #pragma unroll
        for (int i = 0; i < 4; i++)      // 8 A-rows per issue x4 = 32 rows
            GLOAD_LDS(gA + kt * 64 + (size_t)i * 8 * DIM, lA + i * 512);
        #pragma unroll
        for (int i = 0; i < 2; i++)      // 8 B-rows per issue x2 = 16 rows
            GLOAD_LDS(gB + kt * 64 + (size_t)i * 8 * DIM, lB + i * 512);
        __syncthreads();

        #pragma unroll
        for (int ks = 0; ks < 2; ks++) {
            const int pc = (((ks * 4 + quad) ^ (lane & 7)) * 8);
            short8 af0 = *(const short8*)&As[(wn +      lm) * 64 + pc];
            short8 af1 = *(const short8*)&As[(wn + 16 + lm) * 64 + pc];
            #pragma unroll
            for (int j = 0; j < 8; j++) {
                short8 bf = *(const short8*)&Bs[(j * 16 + lm) * 64 + pc];
                acc[0][j] = __builtin_amdgcn_mfma_f32_16x16x32_bf16(af0, bf, acc[0][j], 0, 0, 0);
                acc[1][j] = __builtin_amdgcn_mfma_f32_16x16x32_bf16(af1, bf, acc[1][j], 0, 0, 0);
            }
        }
        __syncthreads();
    }

    // V rows from global (L2-hot)
    float v0[8], v1[8], v2[8];
    #pragma unroll
    for (int j = 0; j < 8; j++) {
        int vc = m0 + j * 16 + lm;
        v0[j] = Tb[vc];
        v1[j] = Tb[MM + vc];
        v2[j] = Tb[2 * MM + vc];
    }

    const size_t slot = (size_t)(b * MSPLIT + qt) * NN;
    // C/D layout (m89/m91): col = lane&15 (m), row = quad*4+reg (n)
    #pragma unroll
    for (int i = 0; i < 2; i++) {
        float l4[4] = {0,0,0,0};
        float o0[4] = {0,0,0,0};
        float o1[4] = {0,0,0,0};
        float o2[4] = {0,0,0,0};
        #pragma unroll
        for (int j = 0; j < 8; j++) {
            #pragma unroll
            for (int r = 0; r < 4; r++) {
                float e = __builtin_amdgcn_exp2f(acc[i][j][r] * SCALE);
                l4[r] += e;
                o0[r] += e * v0[j];
                o1[r] += e * v1[j];
                o2[r] += e * v2[j];
            }
        }
        #pragma unroll
        for (int m = 1; m <= 8; m <<= 1) {
            #pragma unroll
            for (int r = 0; r < 4; r++) {
                l4[r] += __shfl_xor(l4[r], m);
                o0[r] += __shfl_xor(o0[r], m);
                o1[r] += __shfl_xor(o1[r], m);
                o2[r] += __shfl_xor(o2[r], m);
            }
        }
        if (lm == 0) {
            #pragma unroll
            for (int r = 0; r < 4; r++) {
                int n = nt * 256 + wn + i * 16 + quad * 4 + r;
                ((float4*)part)[slot + n] = make_float4(l4[r], o0[r], o1[r], o2[r]);
            }
        }
    }
}

// ---------------- stage-1 reduce: 128 blocks ----------------
__global__ __launch_bounds__(128) void reduce1_kernel(
    const float* __restrict__ part,
    const float* __restrict__ src,       // [B,3,N]
    const float* __restrict__ tgt,       // [B,3,M]
    float* __restrict__ red)             // [b][chunk][18]
{
    const int chunk = blockIdx.x;        // 0..15
    const int b     = blockIdx.y;        // 0..7
    const int t     = threadIdx.x;       // 0..127
    const int n     = chunk * 128 + t;

    const float4* w4 = (const float4*)part;
    const float* S = src + (size_t)b * 3 * NN;
    const float* T = tgt + (size_t)b * 3 * MM;

    float l = 0.f, y0 = 0.f, y1 = 0.f, y2 = 0.f;
    #pragma unroll
    for (int q = 0; q < 16; q++) {
        float4 p = w4[(size_t)(b * 16 + q) * NN + n];
        l += p.x; y0 += p.y; y1 += p.z; y2 += p.w;
    }
    float inv = 1.0f / l;
    float c0 = y0 * inv, c1 = y1 * inv, c2 = y2 * inv;
    float s0 = S[n], s1 = S[NN + n], s2 = S[2 * NN + n];

    float vals[18];
    vals[0] = s0;  vals[1] = s1;  vals[2] = s2;
    vals[3] = c0;  vals[4] = c1;  vals[5] = c2;
    vals[6] = T[n]; vals[7] = T[MM + n]; vals[8] = T[2 * MM + n];
    vals[9]  = s0 * c0; vals[10] = s0 * c1; vals[11] = s0 * c2;
    vals[12] = s1 * c0; vals[13] = s1 * c1; vals[14] = s1 * c2;
    vals[15] = s2 * c0; vals[16] = s2 * c1; vals[17] = s2 * c2;

    #pragma unroll
    for (int m = 1; m <= 32; m <<= 1)
        #pragma unroll
        for (int c = 0; c < 18; c++)
            vals[c] += __shfl_xor(vals[c], m);

    __shared__ float w0[18];
    if (t == 64)
        #pragma unroll
        for (int c = 0; c < 18; c++) w0[c] = vals[c];
    __syncthreads();
    if (t == 0)
        #pragma unroll
        for (int c = 0; c < 18; c++)
            red[(size_t)(b * 16 + chunk) * 18 + c] = vals[c] + w0[c];
}

// ---------------- stage-2: combine 16 chunk-sums, Procrustes ----------------
__global__ __launch_bounds__(64) void procrustes_kernel(
    const float* __restrict__ red,       // [b][chunk][18]
    float* __restrict__ out)             // [72 R][24 t]
{
    const int b = blockIdx.x;
    const int t = threadIdx.x;

    __shared__ float res[18];
    if (t < 18) {
        float a = 0.f;
        #pragma unroll
        for (int q = 0; q < 16; q++)
            a += red[(size_t)(b * 16 + q) * 18 + t];
        res[t] = a;
    }
    __syncthreads();

    if (t == 0) {
        const float invN = 1.0f / (float)NN;
        float mus[3], muc[3], mut[3], H[3][3];
        for (int i = 0; i < 3; i++) {
            mus[i] = res[i] * invN;
            muc[i] = res[3 + i] * invN;
            mut[i] = res[6 + i] * invN;
        }
        for (int i = 0; i < 3; i++)
            for (int j = 0; j < 3; j++)
                H[i][j] = res[9 + i * 3 + j] - (float)NN * mus[i] * muc[j];

        float A[3][3];
        for (int i = 0; i < 3; i++)
            for (int j = 0; j < 3; j++)
                A[i][j] = H[0][i] * H[0][j] + H[1][i] * H[1][j] + H[2][i] * H[2][j];

        float V[3][3] = {{1,0,0},{0,1,0},{0,0,1}};
        for (int sweep = 0; sweep < 6; sweep++) {
            for (int pi = 0; pi < 3; pi++) {
                int p = (pi < 2) ? 0 : 1;
                int q = (pi == 0) ? 1 : 2;
                float apq = A[p][q];
                if (fabsf(apq) < 1e-30f) continue;
                float tau = (A[q][q] - A[p][p]) / (2.0f * apq);
                float tt = (tau >= 0.0f) ? 1.0f / (tau + sqrtf(1.0f + tau * tau))
                                         : -1.0f / (-tau + sqrtf(1.0f + tau * tau));
                float c = 1.0f / sqrtf(1.0f + tt * tt);
                float s = tt * c;
                for (int k = 0; k < 3; k++) {
                    float akp = A[k][p], akq = A[k][q];
                    A[k][p] = c * akp - s * akq;
                    A[k][q] = s * akp + c * akq;
                }
                for (int k = 0; k < 3; k++) {
                    float apk = A[p][k], aqk = A[q][k];
                    A[p][k] = c * apk - s * aqk;
                    A[q][k] = s * apk + c * aqk;
                }
                for (int k = 0; k < 3; k++) {
                    float vkp = V[k][p], vkq = V[k][q];
                    V[k][p] = c * vkp - s * vkq;
                    V[k][q] = s * vkp + c * vkq;
                }
            }
        }

        float lam[3] = {A[0][0], A[1][1], A[2][2]};
        int idx[3] = {0, 1, 2};
        for (int a = 0; a < 2; a++)
            for (int bb = 0; bb < 2 - a; bb++)
                if (lam[idx[bb]] < lam[idx[bb + 1]]) { int tmp = idx[bb]; idx[bb] = idx[bb + 1]; idx[bb + 1] = tmp; }

        float Vc[3][3], U[3][3];
        for (int c = 0; c < 3; c++) {
            float sv = sqrtf(fmaxf(lam[idx[c]], 0.0f));
            float isv = 1.0f / fmaxf(sv, 1e-20f);
            for (int r = 0; r < 3; r++) {
                Vc[r][c] = V[r][idx[c]];
                U[r][c] = (H[r][0] * V[0][idx[c]] + H[r][1] * V[1][idx[c]] + H[r][2] * V[2][idx[c]]) * isv;
            }
        }

        {
            float nrm = rsqrtf(U[0][0]*U[0][0] + U[1][0]*U[1][0] + U[2][0]*U[2][0]);
            for (int r = 0; r < 3; r++) U[r][0] *= nrm;
            float d01 = U[0][0]*U[0][1] + U[1][0]*U[1][1] + U[2][0]*U[2][1];
            for (int r = 0; r < 3; r++) U[r][1] -= d01 * U[r][0];
            nrm = rsqrtf(U[0][1]*U[0][1] + U[1][1]*U[1][1] + U[2][1]*U[2][1]);
            for (int r = 0; r < 3; r++) U[r][1] *= nrm;
            float d02 = U[0][0]*U[0][2] + U[1][0]*U[1][2] + U[2][0]*U[2][2];
            float d12 = U[0][1]*U[0][2] + U[1][1]*U[1][2] + U[2][1]*U[2][2];
            for (int r = 0; r < 3; r++) U[r][2] -= d02 * U[r][0] + d12 * U[r][1];
            nrm = rsqrtf(U[0][2]*U[0][2] + U[1][2]*U[1][2] + U[2][2]*U[2][2]);
            for (int r = 0; r < 3; r++) U[r][2] *= nrm;
        }

        float det = H[0][0]*(H[1][1]*H[2][2] - H[1][2]*H[2][1])
                  - H[0][1]*(H[1][0]*H[2][2] - H[1][2]*H[2][0])
                  + H[0][2]*(H[1][0]*H[2][1] - H[1][1]*H[2][0]);
        float sgn = (det < 0.0f) ? -1.0f : 1.0f;

        float R[3][3];
        for (int i = 0; i < 3; i++)
            for (int j = 0; j < 3; j++)
                R[i][j] = Vc[i][0]*U[j][0] + Vc[i][1]*U[j][1] + sgn * Vc[i][2]*U[j][2];

        for (int i = 0; i < 3; i++)
            for (int j = 0; j < 3; j++)
                out[b * 9 + i * 3 + j] = R[i][j];
        for (int i = 0; i < 3; i++)
            out[BQ * 9 + b * 3 + i] = mut[i] - (R[i][0]*mus[0] + R[i][1]*mus[1] + R[i][2]*mus[2]);
    }
}

extern "C" void kernel_launch(void* const* d_in, const int* in_sizes, int n_in,
                              void* d_out, int out_size, void* d_ws, size_t ws_size,
                              hipStream_t stream) {
    const float* src_emb = (const float*)d_in[0];
    const float* tgt_emb = (const float*)d_in[1];
    const float* src     = (const float*)d_in[2];
    const float* tgt     = (const float*)d_in[3];
    float* out = (float*)d_out;

    float* part = (float*)d_ws;                                            // 4 MiB
    __hip_bfloat16* Abf = (__hip_bfloat16*)((char*)d_ws + (4 << 20));       // 16 MiB
    __hip_bfloat16* Bbf = (__hip_bfloat16*)((char*)d_ws + (20 << 20));      // 16 MiB
    float* red = (float*)((char*)d_ws + (36 << 20));                        // 9 KiB

    dim3 gridT(NN / 64, DIM / 64, 2 * BQ);    // 32 x 8 x 16 = 4096 blocks
    transpose_cast_kernel<<<gridT, 256, 0, stream>>>(src_emb, tgt_emb, Abf, Bbf);

    dim3 gridA(NN / 256, MSPLIT, BQ);         // 8 x 16 x 8 = 1024 blocks
    attn_mfma_kernel<<<gridA, 512, 0, stream>>>(Abf, Bbf, tgt, part);

    dim3 gridR(16, BQ);                       // 128 blocks
    reduce1_kernel<<<gridR, 128, 0, stream>>>(part, src, tgt, red);

    procrustes_kernel<<<BQ, 64, 0, stream>>>(red, out);
}